// Round 9
// baseline (428.499 us; speedup 1.0000x reference)
//
#include <hip/hip_runtime.h>

#define N_NODES 50000
#define D_FEAT 64
#define N_NNZ 800000
#define N_ENT 65536   // 2 * 32768 edge endpoints

// ===== MEASUREMENT ROUND: duplicate-work ablation ==========================
// spmm1/spmm2/gather are idempotent; repeating their bodies REP times makes
// dispatch duration ~ REP * t_kernel, surfacing each above the harness's
// 88us fillBuffer rows in the rocprof top-5. asm memory clobber between reps
// prevents cross-rep CSE (rule: stubbed/duplicated work must stay live).
// REVERT REP TO 1 NEXT ROUND.
#define REP_SPMM1 4
#define REP_SPMM2 4
#define REP_GATHER 3
// ===========================================================================

typedef unsigned int uint32;
typedef unsigned short ushort16;

// Plane strides for plane-major [3][N][64] bf16 tables
#define PLANE_U4 ((size_t)N_NODES * 8)    // in uint4 (16B) units
#define PLANE_US ((size_t)N_NODES * 64)   // in ushort units

// ---- bf16 helpers ---------------------------------------------------------
__device__ __forceinline__ uint32 rne1(float a) {
    uint32 u = __float_as_uint(a);
    return (u + 0x7FFFu + ((u >> 16) & 1u)) >> 16;
}
__device__ __forceinline__ uint32 rne2(float a, float b) {   // pack [a:lo, b:hi]
    return rne1(a) | (rne1(b) << 16);
}
__device__ __forceinline__ float bf_lo(uint32 u) { return __uint_as_float(u << 16); }
__device__ __forceinline__ float bf_hi(uint32 u) { return __uint_as_float(u & 0xFFFF0000u); }
__device__ __forceinline__ void unpack8(const uint4 v, float* f) {
    f[0] = bf_lo(v.x); f[1] = bf_hi(v.x);
    f[2] = bf_lo(v.y); f[3] = bf_hi(v.y);
    f[4] = bf_lo(v.z); f[5] = bf_hi(v.z);
    f[6] = bf_lo(v.w); f[7] = bf_hi(v.w);
}
__device__ __forceinline__ float bf1(ushort16 u) { return __uint_as_float(((uint32)u) << 16); }

// ---------------------------------------------------------------------------
// 1a) CSR row pointers (binary search over sorted adj_row) + per-node scalars
// ---------------------------------------------------------------------------
__global__ void build_rowptr_scal(const int* __restrict__ adj_row,
                                  const float* __restrict__ deg,
                                  int* __restrict__ row_ptr,
                                  float4* __restrict__ scal,
                                  int nnz, int n) {
    int r = blockIdx.x * blockDim.x + threadIdx.x;
    if (r > n) return;
    int lo = 0, hi = nnz;           // first idx with adj_row[idx] >= r
    while (lo < hi) {
        int mid = (lo + hi) >> 1;
        if (adj_row[mid] < r) lo = mid + 1; else hi = mid;
    }
    row_ptr[r] = lo;
    if (r < n) {
        float d  = deg[r];
        float sq = sqrtf(d);
        scal[r] = make_float4(1.0f / d, 1.0f / sq, sq, 0.0f);
    }
}

// 1b) x (fp32) -> xh (bf16 pairs). 50000*64/2 = 1.6M uint32.
__global__ __launch_bounds__(256) void pack_x(const float2* __restrict__ x2,
                                              uint32* __restrict__ xh, int npair) {
    int i = blockIdx.x * blockDim.x + threadIdx.x;
    if (i >= npair) return;
    float2 v = x2[i];
    xh[i] = rne2(v.x, v.y);
}

// ---------------------------------------------------------------------------
// 2) y1 = degrev * spmm(x3). Octet-per-row, 4-way MLP. REP_SPMM1 ablation.
// ---------------------------------------------------------------------------
__global__ __launch_bounds__(256) void spmm1_kernel(
    const uint4* __restrict__ xh, const float4* __restrict__ scal,
    const int* __restrict__ adj_col, const int* __restrict__ row_ptr,
    uint4* __restrict__ y1h, int n) {
    int t    = threadIdx.x & 63;
    int f    = t & 7;                                  // feature block
    int r    = (blockIdx.x * 4 + (threadIdx.x >> 6)) * 8 + (t >> 3);
    if (r >= n) return;

    for (int rep = 0; rep < REP_SPMM1; ++rep) {
        asm volatile("" ::: "memory");                 // no cross-rep CSE

        int s = row_ptr[r], e = row_ptr[r + 1];
        int cnt = e - s;
        float a0[8], a1[8], a2[8];
#pragma unroll
        for (int j = 0; j < 8; ++j) { a0[j] = 0.f; a1[j] = 0.f; a2[j] = 0.f; }

        int i = 0;
        for (; i + 4 <= cnt; i += 4) {
            int c0 = adj_col[s + i];
            int c1 = adj_col[s + i + 1];
            int c2 = adj_col[s + i + 2];
            int c3 = adj_col[s + i + 3];
            uint4 xv0 = xh[(size_t)c0 * 8 + f];
            uint4 xv1 = xh[(size_t)c1 * 8 + f];
            uint4 xv2 = xh[(size_t)c2 * 8 + f];
            uint4 xv3 = xh[(size_t)c3 * 8 + f];
            float4 sc0 = scal[c0];
            float4 sc1 = scal[c1];
            float4 sc2 = scal[c2];
            float4 sc3 = scal[c3];
            float xf0[8], xf1[8], xf2[8], xf3[8];
            unpack8(xv0, xf0); unpack8(xv1, xf1);
            unpack8(xv2, xf2); unpack8(xv3, xf3);
#pragma unroll
            for (int j = 0; j < 8; ++j) {
                a0[j] += (xf0[j] + xf1[j]) + (xf2[j] + xf3[j]);
                a1[j] += (xf0[j] * sc0.y + xf1[j] * sc1.y)
                       + (xf2[j] * sc2.y + xf3[j] * sc3.y);
                a2[j] += (xf0[j] * sc0.z + xf1[j] * sc1.z)
                       + (xf2[j] * sc2.z + xf3[j] * sc3.z);
            }
        }
        for (; i < cnt; ++i) {
            int c = adj_col[s + i];
            uint4 xv = xh[(size_t)c * 8 + f];
            float4 sc = scal[c];
            float xf[8]; unpack8(xv, xf);
#pragma unroll
            for (int j = 0; j < 8; ++j) {
                a0[j] += xf[j];
                a1[j] += xf[j] * sc.y;
                a2[j] += xf[j] * sc.z;
            }
        }

        float dr = scal[r].x;
        size_t base = (size_t)r * 8 + f;
        y1h[base]               = make_uint4(rne2(a0[0]*dr, a0[1]*dr), rne2(a0[2]*dr, a0[3]*dr),
                                             rne2(a0[4]*dr, a0[5]*dr), rne2(a0[6]*dr, a0[7]*dr));
        y1h[base + PLANE_U4]    = make_uint4(rne2(a1[0]*dr, a1[1]*dr), rne2(a1[2]*dr, a1[3]*dr),
                                             rne2(a1[4]*dr, a1[5]*dr), rne2(a1[6]*dr, a1[7]*dr));
        y1h[base + 2*PLANE_U4]  = make_uint4(rne2(a2[0]*dr, a2[1]*dr), rne2(a2[2]*dr, a2[3]*dr),
                                             rne2(a2[4]*dr, a2[5]*dr), rne2(a2[6]*dr, a2[7]*dr));
    }
}

// ---------------------------------------------------------------------------
// 3) y2 = degrev * spmm(y1) - x3, plane-split, 8-way MLP. REP_SPMM2 ablation.
// ---------------------------------------------------------------------------
__global__ __launch_bounds__(256) void spmm2_kernel(
    const float4* __restrict__ x4, const float4* __restrict__ scal,
    const int* __restrict__ adj_col, const int* __restrict__ row_ptr,
    const uint4* __restrict__ y1h, uint4* __restrict__ y2h, int n) {
    int t = threadIdx.x & 63;
    int f = t & 7;
    int r = (blockIdx.x * 4 + (threadIdx.x >> 6)) * 8 + (t >> 3);
    int g = blockIdx.y;
    if (r >= n) return;
    const uint4* yp = y1h + (size_t)g * PLANE_U4;

    for (int rep = 0; rep < REP_SPMM2; ++rep) {
        asm volatile("" ::: "memory");                 // no cross-rep CSE

        int s = row_ptr[r], e = row_ptr[r + 1];
        int cnt = e - s;
        float a[8];
#pragma unroll
        for (int j = 0; j < 8; ++j) a[j] = 0.f;

        int i = 0;
        for (; i + 8 <= cnt; i += 8) {                 // 8 gathers in flight
            int c0 = adj_col[s + i];
            int c1 = adj_col[s + i + 1];
            int c2 = adj_col[s + i + 2];
            int c3 = adj_col[s + i + 3];
            int c4 = adj_col[s + i + 4];
            int c5 = adj_col[s + i + 5];
            int c6 = adj_col[s + i + 6];
            int c7 = adj_col[s + i + 7];
            uint4 b0 = yp[(size_t)c0 * 8 + f];
            uint4 b1 = yp[(size_t)c1 * 8 + f];
            uint4 b2 = yp[(size_t)c2 * 8 + f];
            uint4 b3 = yp[(size_t)c3 * 8 + f];
            uint4 b4 = yp[(size_t)c4 * 8 + f];
            uint4 b5 = yp[(size_t)c5 * 8 + f];
            uint4 b6 = yp[(size_t)c6 * 8 + f];
            uint4 b7 = yp[(size_t)c7 * 8 + f];
            float f0[8], f1[8], f2[8], f3[8], f4[8], f5[8], f6[8], f7[8];
            unpack8(b0, f0); unpack8(b1, f1); unpack8(b2, f2); unpack8(b3, f3);
            unpack8(b4, f4); unpack8(b5, f5); unpack8(b6, f6); unpack8(b7, f7);
#pragma unroll
            for (int j = 0; j < 8; ++j)
                a[j] += ((f0[j] + f1[j]) + (f2[j] + f3[j]))
                      + ((f4[j] + f5[j]) + (f6[j] + f7[j]));
        }
        for (; i + 4 <= cnt; i += 4) {
            int c0 = adj_col[s + i];
            int c1 = adj_col[s + i + 1];
            int c2 = adj_col[s + i + 2];
            int c3 = adj_col[s + i + 3];
            uint4 b0 = yp[(size_t)c0 * 8 + f];
            uint4 b1 = yp[(size_t)c1 * 8 + f];
            uint4 b2 = yp[(size_t)c2 * 8 + f];
            uint4 b3 = yp[(size_t)c3 * 8 + f];
            float f0[8], f1[8], f2[8], f3[8];
            unpack8(b0, f0); unpack8(b1, f1); unpack8(b2, f2); unpack8(b3, f3);
#pragma unroll
            for (int j = 0; j < 8; ++j)
                a[j] += (f0[j] + f1[j]) + (f2[j] + f3[j]);
        }
        for (; i < cnt; ++i) {
            int c = adj_col[s + i];
            uint4 b = yp[(size_t)c * 8 + f];
            float fv[8]; unpack8(b, fv);
#pragma unroll
            for (int j = 0; j < 8; ++j) a[j] += fv[j];
        }

        float4 sc = scal[r];                       // {1/d, rsqrt, sqrt, 0}
        float w = (g == 0) ? 1.0f : ((g == 1) ? sc.y : sc.z);
        float4 xa = x4[(size_t)r * 16 + f * 2];
        float4 xb = x4[(size_t)r * 16 + f * 2 + 1];
        float xr[8] = {xa.x, xa.y, xa.z, xa.w, xb.x, xb.y, xb.z, xb.w};
        float v[8];
#pragma unroll
        for (int j = 0; j < 8; ++j) v[j] = sc.x * a[j] - xr[j] * w;

        uint4* yr = y2h + (size_t)g * PLANE_U4 + (size_t)r * 8 + f;
        yr[0] = make_uint4(rne2(v[0], v[1]), rne2(v[2], v[3]),
                           rne2(v[4], v[5]), rne2(v[6], v[7]));
    }
}

// ---------------------------------------------------------------------------
// 4) Output gather + [64,9] transpose through LDS. REP_GATHER ablation.
// ---------------------------------------------------------------------------
__global__ __launch_bounds__(256) void gather_kernel(
    const float* __restrict__ x, const float4* __restrict__ scal,
    const int* __restrict__ edge, const ushort16* __restrict__ y1h,
    const ushort16* __restrict__ y2h, float* __restrict__ out) {
    __shared__ __align__(16) float lds[4][576];
    int wave = threadIdx.x >> 6;
    int t    = threadIdx.x & 63;
    int ent  = blockIdx.x * 4 + wave;

    for (int rep = 0; rep < REP_GATHER; ++rep) {
        asm volatile("" ::: "memory");                 // no cross-rep CSE

        int n = edge[ent];
        float4 sc = scal[n];                       // {1/d, rsqrt, sqrt, 0}
        float xv = x[n * D_FEAT + t];
        size_t nb = (size_t)n * 64 + t;

        float h[9];
        h[0] = xv;                   h[1] = xv * sc.y;               h[2] = xv * sc.z;
        h[3] = bf1(y1h[nb]);         h[4] = bf1(y1h[nb + PLANE_US]); h[5] = bf1(y1h[nb + 2*PLANE_US]);
        h[6] = bf1(y2h[nb]);         h[7] = bf1(y2h[nb + PLANE_US]); h[8] = bf1(y2h[nb + 2*PLANE_US]);

#pragma unroll
        for (int g = 0; g < 9; ++g) lds[wave][t * 9 + g] = h[g];
        __syncthreads();

        const float4* l4 = (const float4*)lds[wave];
        float4* o4 = (float4*)(out + (size_t)ent * 576);   // 144 float4/entry
        o4[t]      = l4[t];
        o4[t + 64] = l4[t + 64];
        if (t < 16) o4[t + 128] = l4[t + 128];
        __syncthreads();                           // LDS safe for next rep
    }
}

// ---------------------------------------------------------------------------
extern "C" void kernel_launch(void* const* d_in, const int* in_sizes, int n_in,
                              void* d_out, int out_size, void* d_ws, size_t ws_size,
                              hipStream_t stream) {
    const float* x       = (const float*)d_in[0];   // [N, 64]
    const float* deg     = (const float*)d_in[1];   // [N, 1]
    const int*   adj_row = (const int*)d_in[2];     // [nnz] sorted
    const int*   adj_col = (const int*)d_in[3];     // [nnz]
    const int*   edge    = (const int*)d_in[4];     // [2, 32768]
    float* out = (float*)d_out;

    // Workspace (rewritten fully every call)
    char* ws = (char*)d_ws;
    size_t off = 0;
    int*    row_ptr = (int*)ws;            off = ((size_t)(N_NODES + 1) * 4 + 255) & ~(size_t)255;
    float4* scal    = (float4*)(ws + off); off += (size_t)N_NODES * 16;
    uint32* xh      = (uint32*)(ws + off); off += (size_t)N_NODES * 64 * 2;
    off = (off + 255) & ~(size_t)255;
    uint4*  y1h     = (uint4*)(ws + off);  off += (size_t)N_NODES * 192 * 2;
    off = (off + 255) & ~(size_t)255;
    uint4*  y2h     = (uint4*)(ws + off);

    int nblk = (N_NODES + 31) / 32;

    build_rowptr_scal<<<(N_NODES + 1 + 255) / 256, 256, 0, stream>>>(
        adj_row, deg, row_ptr, scal, N_NNZ, N_NODES);
    pack_x<<<(N_NODES * 32 + 255) / 256, 256, 0, stream>>>(
        (const float2*)x, xh, N_NODES * 32);
    spmm1_kernel<<<nblk, 256, 0, stream>>>(
        (const uint4*)xh, scal, adj_col, row_ptr, y1h, N_NODES);
    spmm2_kernel<<<dim3(nblk, 3), 256, 0, stream>>>(
        (const float4*)x, scal, adj_col, row_ptr, y1h, y2h, N_NODES);
    gather_kernel<<<N_ENT / 4, 256, 0, stream>>>(
        x, scal, edge, (const ushort16*)y1h, (const ushort16*)y2h, out);
}

// Round 12
// 261.741 us; speedup vs baseline: 1.6371x; 1.6371x over previous
//
#include <hip/hip_runtime.h>

#define N_NODES 50000
#define D_FEAT 64
#define N_NNZ 800000
#define N_ENT 65536   // 2 * 32768 edge endpoints

typedef unsigned int uint32;
typedef unsigned short ushort16;

// clang ext_vector types: __builtin_nontemporal_store accepts these
// (HIP's uint4/float4 are C++ classes and are rejected -- R11 compile error).
typedef uint32 u32x4 __attribute__((ext_vector_type(4)));
typedef float  f32x4 __attribute__((ext_vector_type(4)));

__device__ __forceinline__ void nt_store_u4(const uint4 v, uint4* p) {
    u32x4 w; w.x = v.x; w.y = v.y; w.z = v.z; w.w = v.w;
    __builtin_nontemporal_store(w, reinterpret_cast<u32x4*>(p));
}
__device__ __forceinline__ void nt_store_f4(const float4 v, float4* p) {
    f32x4 w; w.x = v.x; w.y = v.y; w.z = v.z; w.w = v.w;
    __builtin_nontemporal_store(w, reinterpret_cast<f32x4*>(p));
}

// Plane strides for plane-major [3][N][64] bf16 tables
#define PLANE_U4 ((size_t)N_NODES * 8)    // in uint4 (16B) units
#define PLANE_US ((size_t)N_NODES * 64)   // in ushort units

// ---- bf16 helpers ---------------------------------------------------------
__device__ __forceinline__ uint32 rne1(float a) {
    uint32 u = __float_as_uint(a);
    return (u + 0x7FFFu + ((u >> 16) & 1u)) >> 16;
}
__device__ __forceinline__ uint32 rne2(float a, float b) {   // pack [a:lo, b:hi]
    return rne1(a) | (rne1(b) << 16);
}
__device__ __forceinline__ float bf_lo(uint32 u) { return __uint_as_float(u << 16); }
__device__ __forceinline__ float bf_hi(uint32 u) { return __uint_as_float(u & 0xFFFF0000u); }
__device__ __forceinline__ void unpack8(const uint4 v, float* f) {
    f[0] = bf_lo(v.x); f[1] = bf_hi(v.x);
    f[2] = bf_lo(v.y); f[3] = bf_hi(v.y);
    f[4] = bf_lo(v.z); f[5] = bf_hi(v.z);
    f[6] = bf_lo(v.w); f[7] = bf_hi(v.w);
}
__device__ __forceinline__ float bf1(ushort16 u) { return __uint_as_float(((uint32)u) << 16); }

// ---------------------------------------------------------------------------
// 1) prep: CSR row pointers + per-node scalars + x->bf16 pack, ONE dispatch
//    (was two; build/pack are independent -> merged to cut a launch gap).
// ---------------------------------------------------------------------------
__global__ __launch_bounds__(256) void prep_kernel(
    const int* __restrict__ adj_row, const float* __restrict__ deg,
    const float2* __restrict__ x2,
    int* __restrict__ row_ptr, float4* __restrict__ scal,
    uint32* __restrict__ xh, int nnz, int n, int npair) {
    int i = blockIdx.x * blockDim.x + threadIdx.x;
    if (i < npair) {                     // pack 2 bf16 per thread
        float2 v = x2[i];
        xh[i] = rne2(v.x, v.y);
    }
    if (i <= n) {                        // rowptr via binary search
        int lo = 0, hi = nnz;            // first idx with adj_row[idx] >= i
        while (lo < hi) {
            int mid = (lo + hi) >> 1;
            if (adj_row[mid] < i) lo = mid + 1; else hi = mid;
        }
        row_ptr[i] = lo;
        if (i < n) {
            float d  = deg[i];
            float sq = sqrtf(d);
            scal[i] = make_float4(1.0f / d, 1.0f / sq, sq, 0.0f);
        }
    }
}

// ---------------------------------------------------------------------------
// 2) y1 = degrev * spmm(x3). Octet-per-row, 4-way MLP.
//    NT stores on y1h: write-once stream; keeps xh (the gather table, 6.4MB)
//    resident in L2 instead of being evicted by 19.2MB of y1 write-allocate.
// ---------------------------------------------------------------------------
__global__ __launch_bounds__(256) void spmm1_kernel(
    const uint4* __restrict__ xh, const float4* __restrict__ scal,
    const int* __restrict__ adj_col, const int* __restrict__ row_ptr,
    uint4* __restrict__ y1h, int n) {
    int t    = threadIdx.x & 63;
    int f    = t & 7;                                  // feature block
    int r    = (blockIdx.x * 4 + (threadIdx.x >> 6)) * 8 + (t >> 3);
    if (r >= n) return;

    int s = row_ptr[r], e = row_ptr[r + 1];
    int cnt = e - s;
    float a0[8], a1[8], a2[8];
#pragma unroll
    for (int j = 0; j < 8; ++j) { a0[j] = 0.f; a1[j] = 0.f; a2[j] = 0.f; }

    int i = 0;
    for (; i + 4 <= cnt; i += 4) {
        int c0 = adj_col[s + i];
        int c1 = adj_col[s + i + 1];
        int c2 = adj_col[s + i + 2];
        int c3 = adj_col[s + i + 3];
        uint4 xv0 = xh[(size_t)c0 * 8 + f];
        uint4 xv1 = xh[(size_t)c1 * 8 + f];
        uint4 xv2 = xh[(size_t)c2 * 8 + f];
        uint4 xv3 = xh[(size_t)c3 * 8 + f];
        float4 sc0 = scal[c0];
        float4 sc1 = scal[c1];
        float4 sc2 = scal[c2];
        float4 sc3 = scal[c3];
        float xf0[8], xf1[8], xf2[8], xf3[8];
        unpack8(xv0, xf0); unpack8(xv1, xf1);
        unpack8(xv2, xf2); unpack8(xv3, xf3);
#pragma unroll
        for (int j = 0; j < 8; ++j) {
            a0[j] += (xf0[j] + xf1[j]) + (xf2[j] + xf3[j]);
            a1[j] += (xf0[j] * sc0.y + xf1[j] * sc1.y)
                   + (xf2[j] * sc2.y + xf3[j] * sc3.y);
            a2[j] += (xf0[j] * sc0.z + xf1[j] * sc1.z)
                   + (xf2[j] * sc2.z + xf3[j] * sc3.z);
        }
    }
    for (; i < cnt; ++i) {                         // <=3 scalar tail iters
        int c = adj_col[s + i];
        uint4 xv = xh[(size_t)c * 8 + f];
        float4 sc = scal[c];
        float xf[8]; unpack8(xv, xf);
#pragma unroll
        for (int j = 0; j < 8; ++j) {
            a0[j] += xf[j];
            a1[j] += xf[j] * sc.y;
            a2[j] += xf[j] * sc.z;
        }
    }

    float dr = scal[r].x;
    size_t base = (size_t)r * 8 + f;
    uint4 o0 = make_uint4(rne2(a0[0]*dr, a0[1]*dr), rne2(a0[2]*dr, a0[3]*dr),
                          rne2(a0[4]*dr, a0[5]*dr), rne2(a0[6]*dr, a0[7]*dr));
    uint4 o1 = make_uint4(rne2(a1[0]*dr, a1[1]*dr), rne2(a1[2]*dr, a1[3]*dr),
                          rne2(a1[4]*dr, a1[5]*dr), rne2(a1[6]*dr, a1[7]*dr));
    uint4 o2 = make_uint4(rne2(a2[0]*dr, a2[1]*dr), rne2(a2[2]*dr, a2[3]*dr),
                          rne2(a2[4]*dr, a2[5]*dr), rne2(a2[6]*dr, a2[7]*dr));
    nt_store_u4(o0, &y1h[base]);
    nt_store_u4(o1, &y1h[base + PLANE_U4]);
    nt_store_u4(o2, &y1h[base + 2*PLANE_U4]);
}

// ---------------------------------------------------------------------------
// 3) y2 = degrev * spmm(y1) - x3, plane-split (blockIdx.y = group), 8-way MLP.
//    NT stores on y2h: keeps the 6.4MB y1 plane (gather table) resident in L2
//    instead of being evicted by the y2 write stream.
// ---------------------------------------------------------------------------
__global__ __launch_bounds__(256) void spmm2_kernel(
    const float4* __restrict__ x4, const float4* __restrict__ scal,
    const int* __restrict__ adj_col, const int* __restrict__ row_ptr,
    const uint4* __restrict__ y1h, uint4* __restrict__ y2h, int n) {
    int t = threadIdx.x & 63;
    int f = t & 7;
    int r = (blockIdx.x * 4 + (threadIdx.x >> 6)) * 8 + (t >> 3);
    int g = blockIdx.y;
    if (r >= n) return;
    const uint4* yp = y1h + (size_t)g * PLANE_U4;

    int s = row_ptr[r], e = row_ptr[r + 1];
    int cnt = e - s;
    float a[8];
#pragma unroll
    for (int j = 0; j < 8; ++j) a[j] = 0.f;

    int i = 0;
    for (; i + 8 <= cnt; i += 8) {                 // 8 gathers in flight/lane
        int c0 = adj_col[s + i];
        int c1 = adj_col[s + i + 1];
        int c2 = adj_col[s + i + 2];
        int c3 = adj_col[s + i + 3];
        int c4 = adj_col[s + i + 4];
        int c5 = adj_col[s + i + 5];
        int c6 = adj_col[s + i + 6];
        int c7 = adj_col[s + i + 7];
        uint4 b0 = yp[(size_t)c0 * 8 + f];
        uint4 b1 = yp[(size_t)c1 * 8 + f];
        uint4 b2 = yp[(size_t)c2 * 8 + f];
        uint4 b3 = yp[(size_t)c3 * 8 + f];
        uint4 b4 = yp[(size_t)c4 * 8 + f];
        uint4 b5 = yp[(size_t)c5 * 8 + f];
        uint4 b6 = yp[(size_t)c6 * 8 + f];
        uint4 b7 = yp[(size_t)c7 * 8 + f];
        float f0[8], f1[8], f2[8], f3[8], f4[8], f5[8], f6[8], f7[8];
        unpack8(b0, f0); unpack8(b1, f1); unpack8(b2, f2); unpack8(b3, f3);
        unpack8(b4, f4); unpack8(b5, f5); unpack8(b6, f6); unpack8(b7, f7);
#pragma unroll
        for (int j = 0; j < 8; ++j)
            a[j] += ((f0[j] + f1[j]) + (f2[j] + f3[j]))
                  + ((f4[j] + f5[j]) + (f6[j] + f7[j]));
    }
    for (; i + 4 <= cnt; i += 4) {
        int c0 = adj_col[s + i];
        int c1 = adj_col[s + i + 1];
        int c2 = adj_col[s + i + 2];
        int c3 = adj_col[s + i + 3];
        uint4 b0 = yp[(size_t)c0 * 8 + f];
        uint4 b1 = yp[(size_t)c1 * 8 + f];
        uint4 b2 = yp[(size_t)c2 * 8 + f];
        uint4 b3 = yp[(size_t)c3 * 8 + f];
        float f0[8], f1[8], f2[8], f3[8];
        unpack8(b0, f0); unpack8(b1, f1); unpack8(b2, f2); unpack8(b3, f3);
#pragma unroll
        for (int j = 0; j < 8; ++j)
            a[j] += (f0[j] + f1[j]) + (f2[j] + f3[j]);
    }
    for (; i < cnt; ++i) {                         // <=3 scalar tail iters
        int c = adj_col[s + i];
        uint4 b = yp[(size_t)c * 8 + f];
        float fv[8]; unpack8(b, fv);
#pragma unroll
        for (int j = 0; j < 8; ++j) a[j] += fv[j];
    }

    float4 sc = scal[r];                       // {1/d, rsqrt, sqrt, 0}
    float w = (g == 0) ? 1.0f : ((g == 1) ? sc.y : sc.z);
    float4 xa = x4[(size_t)r * 16 + f * 2];
    float4 xb = x4[(size_t)r * 16 + f * 2 + 1];
    float xr[8] = {xa.x, xa.y, xa.z, xa.w, xb.x, xb.y, xb.z, xb.w};
    float v[8];
#pragma unroll
    for (int j = 0; j < 8; ++j) v[j] = sc.x * a[j] - xr[j] * w;

    uint4 o = make_uint4(rne2(v[0], v[1]), rne2(v[2], v[3]),
                         rne2(v[4], v[5]), rne2(v[6], v[7]));
    nt_store_u4(o, &y2h[(size_t)g * PLANE_U4 + (size_t)r * 8 + f]);
}

// ---------------------------------------------------------------------------
// 4) Output gather + [64,9] transpose through LDS.
//    NT stores on out (151MB, never re-read): stops the output stream from
//    evicting the y1h/y2h gather tables between entity reads.
// ---------------------------------------------------------------------------
__global__ __launch_bounds__(256) void gather_kernel(
    const float* __restrict__ x, const float4* __restrict__ scal,
    const int* __restrict__ edge, const ushort16* __restrict__ y1h,
    const ushort16* __restrict__ y2h, float* __restrict__ out) {
    __shared__ __align__(16) float lds[4][576];
    int wave = threadIdx.x >> 6;
    int t    = threadIdx.x & 63;
    int ent  = blockIdx.x * 4 + wave;

    int n = edge[ent];
    float4 sc = scal[n];                       // {1/d, rsqrt, sqrt, 0}
    float xv = x[n * D_FEAT + t];
    size_t nb = (size_t)n * 64 + t;

    float h[9];
    h[0] = xv;                      h[1] = xv * sc.y;                h[2] = xv * sc.z;
    h[3] = bf1(y1h[nb]);            h[4] = bf1(y1h[nb + PLANE_US]);  h[5] = bf1(y1h[nb + 2*PLANE_US]);
    h[6] = bf1(y2h[nb]);            h[7] = bf1(y2h[nb + PLANE_US]);  h[8] = bf1(y2h[nb + 2*PLANE_US]);

#pragma unroll
    for (int g = 0; g < 9; ++g) lds[wave][t * 9 + g] = h[g];  // 2-way alias: free
    __syncthreads();

    const float4* l4 = (const float4*)lds[wave];
    float4* o4 = (float4*)(out + (size_t)ent * 576);   // 144 float4 per entry
    nt_store_f4(l4[t],       &o4[t]);
    nt_store_f4(l4[t + 64],  &o4[t + 64]);
    if (t < 16) nt_store_f4(l4[t + 128], &o4[t + 128]);
}

// ---------------------------------------------------------------------------
extern "C" void kernel_launch(void* const* d_in, const int* in_sizes, int n_in,
                              void* d_out, int out_size, void* d_ws, size_t ws_size,
                              hipStream_t stream) {
    const float* x       = (const float*)d_in[0];   // [N, 64]
    const float* deg     = (const float*)d_in[1];   // [N, 1]
    const int*   adj_row = (const int*)d_in[2];     // [nnz] sorted
    const int*   adj_col = (const int*)d_in[3];     // [nnz]
    const int*   edge    = (const int*)d_in[4];     // [2, 32768]
    float* out = (float*)d_out;

    // Workspace (rewritten fully every call):
    //   row_ptr : (N+1) int        scal : N float4
    //   xh      : N*64 bf16        y1h  : [3][N][64] bf16   y2h : [3][N][64] bf16
    char* ws = (char*)d_ws;
    size_t off = 0;
    int*    row_ptr = (int*)ws;            off = ((size_t)(N_NODES + 1) * 4 + 255) & ~(size_t)255;
    float4* scal    = (float4*)(ws + off); off += (size_t)N_NODES * 16;
    uint32* xh      = (uint32*)(ws + off); off += (size_t)N_NODES * 64 * 2;
    off = (off + 255) & ~(size_t)255;
    uint4*  y1h     = (uint4*)(ws + off);  off += (size_t)N_NODES * 192 * 2;
    off = (off + 255) & ~(size_t)255;
    uint4*  y2h     = (uint4*)(ws + off);

    int nblk = (N_NODES + 31) / 32;
    int npair = N_NODES * 32;

    prep_kernel<<<(npair + 255) / 256, 256, 0, stream>>>(
        adj_row, deg, (const float2*)x, row_ptr, scal, xh,
        N_NNZ, N_NODES, npair);
    spmm1_kernel<<<nblk, 256, 0, stream>>>(
        (const uint4*)xh, scal, adj_col, row_ptr, y1h, N_NODES);
    spmm2_kernel<<<dim3(nblk, 3), 256, 0, stream>>>(
        (const float4*)x, scal, adj_col, row_ptr, y1h, y2h, N_NODES);
    gather_kernel<<<N_ENT / 4, 256, 0, stream>>>(
        x, scal, edge, (const ushort16*)y1h, (const ushort16*)y2h, out);
}

// Round 13
// 252.418 us; speedup vs baseline: 1.6976x; 1.0369x over previous
//
#include <hip/hip_runtime.h>

#define N_NODES 50000
#define D_FEAT 64
#define N_NNZ 800000
#define N_ENT 65536   // 2 * 32768 edge endpoints

typedef unsigned int uint32;
typedef unsigned short ushort16;

// clang ext_vector for __builtin_nontemporal_store (HIP float4 is a class
// and is rejected -- R11). NT is used ONLY on `out` (write-once, never
// re-read by us). R12 measured: NT on y1h/y2h REGRESSES (-5us) because
// those tables are re-read by the next kernel through L2.
typedef float f32x4 __attribute__((ext_vector_type(4)));
__device__ __forceinline__ void nt_store_f4(const float4 v, float4* p) {
    f32x4 w; w.x = v.x; w.y = v.y; w.z = v.z; w.w = v.w;
    __builtin_nontemporal_store(w, reinterpret_cast<f32x4*>(p));
}

// Plane strides for plane-major [3][N][64] bf16 tables
#define PLANE_U4 ((size_t)N_NODES * 8)    // in uint4 (16B) units
#define PLANE_US ((size_t)N_NODES * 64)   // in ushort units

// ---- bf16 helpers ---------------------------------------------------------
__device__ __forceinline__ uint32 rne1(float a) {
    uint32 u = __float_as_uint(a);
    return (u + 0x7FFFu + ((u >> 16) & 1u)) >> 16;
}
__device__ __forceinline__ uint32 rne2(float a, float b) {   // pack [a:lo, b:hi]
    return rne1(a) | (rne1(b) << 16);
}
__device__ __forceinline__ float bf_lo(uint32 u) { return __uint_as_float(u << 16); }
__device__ __forceinline__ float bf_hi(uint32 u) { return __uint_as_float(u & 0xFFFF0000u); }
__device__ __forceinline__ void unpack8(const uint4 v, float* f) {
    f[0] = bf_lo(v.x); f[1] = bf_hi(v.x);
    f[2] = bf_lo(v.y); f[3] = bf_hi(v.y);
    f[4] = bf_lo(v.z); f[5] = bf_hi(v.z);
    f[6] = bf_lo(v.w); f[7] = bf_hi(v.w);
}
__device__ __forceinline__ float bf1(ushort16 u) { return __uint_as_float(((uint32)u) << 16); }

// ---------------------------------------------------------------------------
// 1) prep: CSR row pointers + per-node scalars + x->bf16 pack, ONE dispatch.
// ---------------------------------------------------------------------------
__global__ __launch_bounds__(256) void prep_kernel(
    const int* __restrict__ adj_row, const float* __restrict__ deg,
    const float2* __restrict__ x2,
    int* __restrict__ row_ptr, float4* __restrict__ scal,
    uint32* __restrict__ xh, int nnz, int n, int npair) {
    int i = blockIdx.x * blockDim.x + threadIdx.x;
    if (i < npair) {                     // pack 2 bf16 per thread
        float2 v = x2[i];
        xh[i] = rne2(v.x, v.y);
    }
    if (i <= n) {                        // rowptr via binary search
        int lo = 0, hi = nnz;            // first idx with adj_row[idx] >= i
        while (lo < hi) {
            int mid = (lo + hi) >> 1;
            if (adj_row[mid] < i) lo = mid + 1; else hi = mid;
        }
        row_ptr[i] = lo;
        if (i < n) {
            float d  = deg[i];
            float sq = sqrtf(d);
            scal[i] = make_float4(1.0f / d, 1.0f / sq, sq, 0.0f);
        }
    }
}

// ---------------------------------------------------------------------------
// 2) y1 = degrev * spmm(x3). Octet-per-row, 4-way MLP. Plain stores (L2-
//    forwarded to spmm2/gather, which re-read y1h).
// ---------------------------------------------------------------------------
__global__ __launch_bounds__(256) void spmm1_kernel(
    const uint4* __restrict__ xh, const float4* __restrict__ scal,
    const int* __restrict__ adj_col, const int* __restrict__ row_ptr,
    uint4* __restrict__ y1h, int n) {
    int t    = threadIdx.x & 63;
    int f    = t & 7;                                  // feature block
    int r    = (blockIdx.x * 4 + (threadIdx.x >> 6)) * 8 + (t >> 3);
    if (r >= n) return;

    int s = row_ptr[r], e = row_ptr[r + 1];
    int cnt = e - s;
    float a0[8], a1[8], a2[8];
#pragma unroll
    for (int j = 0; j < 8; ++j) { a0[j] = 0.f; a1[j] = 0.f; a2[j] = 0.f; }

    int i = 0;
    for (; i + 4 <= cnt; i += 4) {
        int c0 = adj_col[s + i];
        int c1 = adj_col[s + i + 1];
        int c2 = adj_col[s + i + 2];
        int c3 = adj_col[s + i + 3];
        uint4 xv0 = xh[(size_t)c0 * 8 + f];
        uint4 xv1 = xh[(size_t)c1 * 8 + f];
        uint4 xv2 = xh[(size_t)c2 * 8 + f];
        uint4 xv3 = xh[(size_t)c3 * 8 + f];
        float4 sc0 = scal[c0];
        float4 sc1 = scal[c1];
        float4 sc2 = scal[c2];
        float4 sc3 = scal[c3];
        float xf0[8], xf1[8], xf2[8], xf3[8];
        unpack8(xv0, xf0); unpack8(xv1, xf1);
        unpack8(xv2, xf2); unpack8(xv3, xf3);
#pragma unroll
        for (int j = 0; j < 8; ++j) {
            a0[j] += (xf0[j] + xf1[j]) + (xf2[j] + xf3[j]);
            a1[j] += (xf0[j] * sc0.y + xf1[j] * sc1.y)
                   + (xf2[j] * sc2.y + xf3[j] * sc3.y);
            a2[j] += (xf0[j] * sc0.z + xf1[j] * sc1.z)
                   + (xf2[j] * sc2.z + xf3[j] * sc3.z);
        }
    }
    for (; i < cnt; ++i) {                         // <=3 scalar tail iters
        int c = adj_col[s + i];
        uint4 xv = xh[(size_t)c * 8 + f];
        float4 sc = scal[c];
        float xf[8]; unpack8(xv, xf);
#pragma unroll
        for (int j = 0; j < 8; ++j) {
            a0[j] += xf[j];
            a1[j] += xf[j] * sc.y;
            a2[j] += xf[j] * sc.z;
        }
    }

    float dr = scal[r].x;
    size_t base = (size_t)r * 8 + f;
    y1h[base]               = make_uint4(rne2(a0[0]*dr, a0[1]*dr), rne2(a0[2]*dr, a0[3]*dr),
                                         rne2(a0[4]*dr, a0[5]*dr), rne2(a0[6]*dr, a0[7]*dr));
    y1h[base + PLANE_U4]    = make_uint4(rne2(a1[0]*dr, a1[1]*dr), rne2(a1[2]*dr, a1[3]*dr),
                                         rne2(a1[4]*dr, a1[5]*dr), rne2(a1[6]*dr, a1[7]*dr));
    y1h[base + 2*PLANE_U4]  = make_uint4(rne2(a2[0]*dr, a2[1]*dr), rne2(a2[2]*dr, a2[3]*dr),
                                         rne2(a2[4]*dr, a2[5]*dr), rne2(a2[6]*dr, a2[7]*dr));
}

// ---------------------------------------------------------------------------
// 3) y2 = degrev * spmm(y1) - x3, plane-split (blockIdx.y = group), 8-way MLP.
//    Plain stores (y2h is re-read by gather through L2).
// ---------------------------------------------------------------------------
__global__ __launch_bounds__(256) void spmm2_kernel(
    const float4* __restrict__ x4, const float4* __restrict__ scal,
    const int* __restrict__ adj_col, const int* __restrict__ row_ptr,
    const uint4* __restrict__ y1h, uint4* __restrict__ y2h, int n) {
    int t = threadIdx.x & 63;
    int f = t & 7;
    int r = (blockIdx.x * 4 + (threadIdx.x >> 6)) * 8 + (t >> 3);
    int g = blockIdx.y;
    if (r >= n) return;
    const uint4* yp = y1h + (size_t)g * PLANE_U4;

    int s = row_ptr[r], e = row_ptr[r + 1];
    int cnt = e - s;
    float a[8];
#pragma unroll
    for (int j = 0; j < 8; ++j) a[j] = 0.f;

    int i = 0;
    for (; i + 8 <= cnt; i += 8) {                 // 8 gathers in flight/lane
        int c0 = adj_col[s + i];
        int c1 = adj_col[s + i + 1];
        int c2 = adj_col[s + i + 2];
        int c3 = adj_col[s + i + 3];
        int c4 = adj_col[s + i + 4];
        int c5 = adj_col[s + i + 5];
        int c6 = adj_col[s + i + 6];
        int c7 = adj_col[s + i + 7];
        uint4 b0 = yp[(size_t)c0 * 8 + f];
        uint4 b1 = yp[(size_t)c1 * 8 + f];
        uint4 b2 = yp[(size_t)c2 * 8 + f];
        uint4 b3 = yp[(size_t)c3 * 8 + f];
        uint4 b4 = yp[(size_t)c4 * 8 + f];
        uint4 b5 = yp[(size_t)c5 * 8 + f];
        uint4 b6 = yp[(size_t)c6 * 8 + f];
        uint4 b7 = yp[(size_t)c7 * 8 + f];
        float f0[8], f1[8], f2[8], f3[8], f4[8], f5[8], f6[8], f7[8];
        unpack8(b0, f0); unpack8(b1, f1); unpack8(b2, f2); unpack8(b3, f3);
        unpack8(b4, f4); unpack8(b5, f5); unpack8(b6, f6); unpack8(b7, f7);
#pragma unroll
        for (int j = 0; j < 8; ++j)
            a[j] += ((f0[j] + f1[j]) + (f2[j] + f3[j]))
                  + ((f4[j] + f5[j]) + (f6[j] + f7[j]));
    }
    for (; i + 4 <= cnt; i += 4) {
        int c0 = adj_col[s + i];
        int c1 = adj_col[s + i + 1];
        int c2 = adj_col[s + i + 2];
        int c3 = adj_col[s + i + 3];
        uint4 b0 = yp[(size_t)c0 * 8 + f];
        uint4 b1 = yp[(size_t)c1 * 8 + f];
        uint4 b2 = yp[(size_t)c2 * 8 + f];
        uint4 b3 = yp[(size_t)c3 * 8 + f];
        float f0[8], f1[8], f2[8], f3[8];
        unpack8(b0, f0); unpack8(b1, f1); unpack8(b2, f2); unpack8(b3, f3);
#pragma unroll
        for (int j = 0; j < 8; ++j)
            a[j] += (f0[j] + f1[j]) + (f2[j] + f3[j]);
    }
    for (; i < cnt; ++i) {                         // <=3 scalar tail iters
        int c = adj_col[s + i];
        uint4 b = yp[(size_t)c * 8 + f];
        float fv[8]; unpack8(b, fv);
#pragma unroll
        for (int j = 0; j < 8; ++j) a[j] += fv[j];
    }

    float4 sc = scal[r];                       // {1/d, rsqrt, sqrt, 0}
    float w = (g == 0) ? 1.0f : ((g == 1) ? sc.y : sc.z);
    float4 xa = x4[(size_t)r * 16 + f * 2];
    float4 xb = x4[(size_t)r * 16 + f * 2 + 1];
    float xr[8] = {xa.x, xa.y, xa.z, xa.w, xb.x, xb.y, xb.z, xb.w};
    float v[8];
#pragma unroll
    for (int j = 0; j < 8; ++j) v[j] = sc.x * a[j] - xr[j] * w;

    uint4* yr = y2h + (size_t)g * PLANE_U4 + (size_t)r * 8 + f;
    yr[0] = make_uint4(rne2(v[0], v[1]), rne2(v[2], v[3]),
                       rne2(v[4], v[5]), rne2(v[6], v[7]));
}

// ---------------------------------------------------------------------------
// 4) Output gather + [64,9] transpose through LDS.
//    NT stores on out ONLY (151MB, never re-read): stops the output stream
//    from evicting the y1h/y2h gather tables it is reading from L2.
// ---------------------------------------------------------------------------
__global__ __launch_bounds__(256) void gather_kernel(
    const float* __restrict__ x, const float4* __restrict__ scal,
    const int* __restrict__ edge, const ushort16* __restrict__ y1h,
    const ushort16* __restrict__ y2h, float* __restrict__ out) {
    __shared__ __align__(16) float lds[4][576];
    int wave = threadIdx.x >> 6;
    int t    = threadIdx.x & 63;
    int ent  = blockIdx.x * 4 + wave;

    int n = edge[ent];
    float4 sc = scal[n];                       // {1/d, rsqrt, sqrt, 0}
    float xv = x[n * D_FEAT + t];
    size_t nb = (size_t)n * 64 + t;

    float h[9];
    h[0] = xv;                      h[1] = xv * sc.y;                h[2] = xv * sc.z;
    h[3] = bf1(y1h[nb]);            h[4] = bf1(y1h[nb + PLANE_US]);  h[5] = bf1(y1h[nb + 2*PLANE_US]);
    h[6] = bf1(y2h[nb]);            h[7] = bf1(y2h[nb + PLANE_US]);  h[8] = bf1(y2h[nb + 2*PLANE_US]);

#pragma unroll
    for (int g = 0; g < 9; ++g) lds[wave][t * 9 + g] = h[g];  // 2-way alias: free
    __syncthreads();

    const float4* l4 = (const float4*)lds[wave];
    float4* o4 = (float4*)(out + (size_t)ent * 576);   // 144 float4 per entry
    nt_store_f4(l4[t],       &o4[t]);
    nt_store_f4(l4[t + 64],  &o4[t + 64]);
    if (t < 16) nt_store_f4(l4[t + 128], &o4[t + 128]);
}

// ---------------------------------------------------------------------------
extern "C" void kernel_launch(void* const* d_in, const int* in_sizes, int n_in,
                              void* d_out, int out_size, void* d_ws, size_t ws_size,
                              hipStream_t stream) {
    const float* x       = (const float*)d_in[0];   // [N, 64]
    const float* deg     = (const float*)d_in[1];   // [N, 1]
    const int*   adj_row = (const int*)d_in[2];     // [nnz] sorted
    const int*   adj_col = (const int*)d_in[3];     // [nnz]
    const int*   edge    = (const int*)d_in[4];     // [2, 32768]
    float* out = (float*)d_out;

    // Workspace (rewritten fully every call):
    //   row_ptr : (N+1) int        scal : N float4
    //   xh      : N*64 bf16        y1h  : [3][N][64] bf16   y2h : [3][N][64] bf16
    char* ws = (char*)d_ws;
    size_t off = 0;
    int*    row_ptr = (int*)ws;            off = ((size_t)(N_NODES + 1) * 4 + 255) & ~(size_t)255;
    float4* scal    = (float4*)(ws + off); off += (size_t)N_NODES * 16;
    uint32* xh      = (uint32*)(ws + off); off += (size_t)N_NODES * 64 * 2;
    off = (off + 255) & ~(size_t)255;
    uint4*  y1h     = (uint4*)(ws + off);  off += (size_t)N_NODES * 192 * 2;
    off = (off + 255) & ~(size_t)255;
    uint4*  y2h     = (uint4*)(ws + off);

    int nblk = (N_NODES + 31) / 32;
    int npair = N_NODES * 32;

    prep_kernel<<<(npair + 255) / 256, 256, 0, stream>>>(
        adj_row, deg, (const float2*)x, row_ptr, scal, xh,
        N_NNZ, N_NODES, npair);
    spmm1_kernel<<<nblk, 256, 0, stream>>>(
        (const uint4*)xh, scal, adj_col, row_ptr, y1h, N_NODES);
    spmm2_kernel<<<dim3(nblk, 3), 256, 0, stream>>>(
        (const float4*)x, scal, adj_col, row_ptr, y1h, y2h, N_NODES);
    gather_kernel<<<N_ENT / 4, 256, 0, stream>>>(
        x, scal, edge, (const ushort16*)y1h, (const ushort16*)y2h, out);
}